// Round 8
// baseline (382.223 us; speedup 1.0000x reference)
//
#include <hip/hip_runtime.h>
#include <hip/hip_bf16.h>
#include <cstdint>
#include <cstddef>

using bf16 = __hip_bfloat16;
#define DEV __device__ __forceinline__

typedef short s16x8 __attribute__((ext_vector_type(8)));
typedef float f32x4 __attribute__((ext_vector_type(4)));

DEV float b2f(bf16 x){ return __bfloat162float(x); }
DEV bf16  f2b(float x){ return __float2bfloat16(x); }
DEV float u2f(unsigned u){ union{unsigned u; float f;} c; c.u=u; return c.f; }
DEV unsigned f2u(float f){ union{float f; unsigned u;} c; c.f=f; return c.u; }
DEV unsigned short f2bu(float f){ unsigned u = f2u(f); u += 0x7FFFu + ((u>>16)&1u); return (unsigned short)(u>>16); }
DEV float sigm(float x){ return 1.f/(1.f+__expf(-x)); }
DEV int get_bf(const void* ln1g){ return ((*(const unsigned*)ln1g) & 0xFFFFu) == 0x3F80u; }

DEV float ld(const void* p, long i, int bf){
  return bf ? b2f(((const bf16*)p)[i]) : ((const float*)p)[i];
}
DEV void st(void* p, long i, float v, int bf){
  if (bf) ((bf16*)p)[i] = f2b(v); else ((float*)p)[i] = v;
}

constexpr float IMGX = 100.0f;
constexpr float IMGY = 56.0f;
constexpr float LOG_EPS = -15.942385f;
constexpr float BIN = 53.0f/1056.0f;
constexpr int NC = 35;
constexpr int CK = 160;
constexpr int NSLICE = 3;

// ---- fp32 weight buffer offsets (floats) ----
constexpr int WO_SAQKVW = 0;
constexpr int WO_SAQKVB = 98304;
constexpr int WO_SAOW   = 99072;
constexpr int WO_SAOB   = 131840;
constexpr int WO_CAQKVW = 132096;
constexpr int WO_CAQKVB = 230400;
constexpr int WO_CAOW   = 231168;
constexpr int WO_CAOB   = 263936;
constexpr int WO_LN1G   = 264192;
constexpr int WO_LN1B   = 264448;
constexpr int WO_LN2G   = 264704;
constexpr int WO_LN2B   = 264960;
constexpr int WO_LN3G   = 265216;
constexpr int WO_LN3B   = 265472;
constexpr int WO_FW1    = 265728;
constexpr int WO_FB1    = 331264;
constexpr int WO_FW2    = 331776;
constexpr int WO_FB2    = 397312;
constexpr int WO_QW1    = 397568;
constexpr int WO_QB1    = 398080;
constexpr int WO_QW2    = 398336;
constexpr int WO_QB2    = 431104;
constexpr int WO_KW1    = 431360;
constexpr int WO_KB1    = 431872;
constexpr int WO_KB2    = 432128;
constexpr int WO_PW1    = 432384;
constexpr int WO_PB1    = 448768;
constexpr int WO_PW2    = 448896;
constexpr int WO_PB2    = 449664;
constexpr int W_TOTAL   = 449680;

// ---- workspace layout (floats) ----
constexpr size_t OFF_Q    = 0;
constexpr size_t OFF_QPE  = 25600;
constexpr size_t OFF_QCA  = 51200;
constexpr size_t OFF_TMP  = 76800;
constexpr size_t OFF_PM   = 153600;
constexpr size_t OFF_PS   = 209600;
constexpr size_t OFF_PO   = 265600;
constexpr size_t OFF_FPOS = 1161600;
constexpr size_t OFF_CTR  = 1172800;
constexpr size_t OFF_SIG  = 1173200;
constexpr size_t OFF_QL   = 1173400;
constexpr size_t OFF_WB   = 1174624;
constexpr size_t F_TOTAL  = OFF_WB + W_TOTAL;
// bf16 region (elements):
constexpr size_t B_KEYS = 0;          // 33600*128
constexpr size_t B_KH   = 4300800;
constexpr size_t B_VH   = 8601600;
constexpr size_t B_KPE  = 12902400;   // 5600*128
constexpr size_t B_WKVT = 13619200;   // 2*256*128
constexpr size_t B_KW2T = 13684736;   // 2*128*128

DEV void unpack2(unsigned u, float* f){ f[0]=u2f(u<<16); f[1]=u2f(u&0xffff0000u); }

DEV float wsum64(float v){
  #pragma unroll
  for (int off=32; off; off>>=1) v += __shfl_xor(v, off);
  return v;
}

// ================= params bundle =================
struct P {
  const void *nifp, *iff, *niqp, *ln1g;
  const int *view, *qlp;
  const float *wb;
  float *q, *qpe, *qca, *tmp, *pm, *ps, *po, *fpos, *ctr, *sig2;
  const bf16 *kw2T, *wkvT, *keys;
  bf16 *kh, *vh, *kpe;
  void *out;
};

// ================= weight conversion + qlist =================
struct Seg { const void* src; int off; int n; };
struct CvtArgs { Seg s[29]; };

__global__ void k_cvt(CvtArgs a, float* dst, int* qlp, const int* view, const void* ln1g){
  if (blockIdx.x == 29){
    int t = threadIdx.x;
    if (blockIdx.y == 0 && t < 6){
      int cnt = 0;
      for (int i = 0; i < 200; ++i)
        if (view[i] == t) qlp[8 + t*200 + cnt++] = i;
      qlp[t] = cnt;
    }
    return;
  }
  int bf = get_bf(ln1g);
  Seg sg = a.s[blockIdx.x];
  for (int i = blockIdx.y*blockDim.x + threadIdx.x; i < sg.n; i += gridDim.y*blockDim.x)
    dst[sg.off + i] = ld(sg.src, i, bf);
}

__global__ __launch_bounds__(128) void k_wT(const void* __restrict__ caw, const void* __restrict__ kw2,
                                            bf16* __restrict__ wkvT, bf16* __restrict__ kw2T,
                                            const void* __restrict__ ln1g){
  int bf = get_bf(ln1g);
  int c = blockIdx.x, l = blockIdx.y, k = threadIdx.x;
  if (c < 256){
    wkvT[((size_t)l*256 + c)*128 + k] = f2b(ld(caw, (long)l*49152 + (long)k*384 + 128 + c, bf));
  } else {
    int cc = c - 256;
    kw2T[((size_t)l*128 + cc)*128 + k] = f2b(ld(kw2, (long)l*16384 + (long)k*128 + cc, bf));
  }
}

// ================= transpose iff -> keys (row-major [v*5600+k][128]) =================
__global__ void k_transpose(const void* __restrict__ iff, bf16* __restrict__ keys,
                            const void* __restrict__ ln1g){
  __shared__ float t[32][33];
  int bf = get_bf(ln1g);
  int k0 = blockIdx.x*32, c0 = blockIdx.y*32, v = blockIdx.z;
  int tx = threadIdx.x, ty = threadIdx.y;
  #pragma unroll
  for (int i=0;i<4;++i){
    int c = c0 + ty + i*8;
    t[ty+i*8][tx] = ld(iff, (long)(v*128 + c)*5600 + k0 + tx, bf);
  }
  __syncthreads();
  #pragma unroll
  for (int i=0;i<4;++i){
    int k = k0 + ty + i*8;
    keys[(size_t)(v*5600 + k)*128 + c0 + tx] = f2b(t[tx][ty+i*8]);
  }
}

// ================= prep2: centers/inverse/pos3d + q-init + pred0 sigma + fpos =================
__global__ __launch_bounds__(128) void k_prep2(
    const void* __restrict__ niqp, const void* __restrict__ l2i, const void* __restrict__ nifp,
    const int* __restrict__ view, const void* __restrict__ iqf,
    float* __restrict__ ctr, float* __restrict__ fpos, float* __restrict__ q,
    const float* __restrict__ wb, float* __restrict__ is2p,
    void* __restrict__ out, const void* __restrict__ ln1g){
  __shared__ float M[16];
  __shared__ float cs[2];
  __shared__ float xs[128];
  __shared__ float redw6[12];
  __shared__ float bbv[8];
  int bf = get_bf(ln1g);
  int n = blockIdx.x, t = threadIdx.x;
  if (t < 28){
    int k = n*28 + t;
    fpos[2*k]   = sigm(ld(nifp,2*k,bf))*IMGX - 0.5f;
    fpos[2*k+1] = sigm(ld(nifp,2*k+1,bf))*IMGY - 0.5f;
  }
  float xv = ld(iqf, (long)t*200 + n, bf);
  q[(size_t)n*128 + t] = xv;
  xs[t] = xv;
  if (t == 0){
    float p0 = ld(niqp,2*n,bf), p1 = ld(niqp,2*n+1,bf);
    float cx = sigm(p0)*IMGX, cy = sigm(p1)*IMGY;
    ctr[2*n] = cx; ctr[2*n+1] = cy;
    cs[0] = cx; cs[1] = cy;
    st(out, 25600 + 2*n,   p0, bf);
    st(out, 25600 + 2*n+1, p1, bf);
    int v = view[n];
    float a[4][8];
    for (int i=0;i<4;++i)
      for (int jj=0;jj<4;++jj){ a[i][jj] = ld(l2i, v*16+i*4+jj, bf); a[i][4+jj] = (i==jj)?1.f:0.f; }
    for (int col=0; col<4; ++col){
      int p = col; float best = fabsf(a[col][col]);
      for (int r=col+1;r<4;++r){ float tt=fabsf(a[r][col]); if (tt>best){best=tt;p=r;} }
      if (p!=col) for (int jj=0;jj<8;++jj){ float tt=a[col][jj]; a[col][jj]=a[p][jj]; a[p][jj]=tt; }
      float inv = 1.f/a[col][col];
      for (int jj=0;jj<8;++jj) a[col][jj]*=inv;
      for (int r=0;r<4;++r){
        if (r==col) continue;
        float f = a[r][col];
        for (int jj=0;jj<8;++jj) a[r][jj] -= f*a[col][jj];
      }
    }
    for (int i=0;i<4;++i) for (int jj=0;jj<4;++jj) M[i*4+jj] = a[i][4+jj];
  }
  __syncthreads();
  if (t < 32){
    int d = t;
    float px = cs[0]*8.f, py = cs[1]*8.f;
    float dep = 1.f + BIN * (float)d * (float)(d+1);
    float x = px*dep, y = py*dep;
    #pragma unroll
    for (int i=0;i<3;++i){
      float val = M[i*4]*x + M[i*4+1]*y + M[i*4+2]*dep + M[i*4+3];
      st(out, 26000 + n*96 + d*3 + i, val, bf);
    }
  }
  float a0 = wb[WO_PB1 + t], a1 = 0.f, a2 = 0.f, a3 = 0.f;
  const float* W = wb + WO_PW1;
  #pragma unroll 8
  for (int k = 0; k < 128; k += 4){
    a0 = fmaf(xs[k],   W[k*128 + t],     a0);
    a1 = fmaf(xs[k+1], W[(k+1)*128 + t], a1);
    a2 = fmaf(xs[k+2], W[(k+2)*128 + t], a2);
    a3 = fmaf(xs[k+3], W[(k+3)*128 + t], a3);
  }
  float x = fmaxf((a0+a1)+(a2+a3), 0.f);
  #pragma unroll
  for (int c=0;c<6;++c){
    float val = wsum64(x * wb[WO_PW2 + t*6 + c]);
    if ((t&63)==0) redw6[(t>>6)*6 + c] = val;
  }
  __syncthreads();
  if (t < 6) bbv[t] = redw6[t] + redw6[6+t] + wb[WO_PB2 + t];
  __syncthreads();
  if (t == 0){
    float dxv = sigm(bbv[2]) * IMGX;
    float dyv = sigm(bbv[3]) * IMGY;
    float rad = ceilf(sqrtf(dxv*dxv + dyv*dyv) * 0.5f);
    float sg = (rad*2.f + 1.f) * (1.f/6.f);
    is2p[n] = 1.f/(2.f*sg*sg);
  }
}

// ================= stage bodies =================

// kpe MFMA (writes bf16 kpe), 256 threads, LDS 17.9 KB
DEV void kpe_block(int b, int t, unsigned char* smem, const P& p, int l, int bf){
  constexpr int XP = 136;
  unsigned short* xs = (unsigned short*)smem;
  float2* pr = (float2*)(xs + 64*XP);
  int r0 = b * 64;
  if (t < 64){
    int k = r0 + t; if (k > 5599) k = 5599;
    pr[t] = make_float2(ld(p.nifp,2*k,bf), ld(p.nifp,2*k+1,bf));
  }
  __syncthreads();
  const float* w1 = p.wb + WO_KW1 + l*256;
  const float* b1 = p.wb + WO_KB1 + l*128;
  for (int idx = t; idx < 64*64; idx += 256){
    int r = idx >> 6, c2 = (idx & 63)*2;
    float2 pp = pr[r];
    #pragma unroll
    for (int u=0;u<2;++u){
      int c = c2+u;
      float a = fmaf(pp.x, w1[c], fmaf(pp.y, w1[128+c], b1[c]));
      xs[r*XP + c] = f2bu(fmaxf(a, 0.f));
    }
  }
  int wv = t >> 6;
  int lane = t & 63;
  int l16 = lane & 15, quad = lane >> 4;
  __syncthreads();
  f32x4 acc[4][2];
  #pragma unroll
  for (int mt=0;mt<4;++mt)
    #pragma unroll
    for (int nt=0;nt<2;++nt) acc[mt][nt] = (f32x4){0.f,0.f,0.f,0.f};
  #pragma unroll
  for (int kc = 0; kc < 4; ++kc){
    s16x8 bfr[2];
    #pragma unroll
    for (int nt = 0; nt < 2; ++nt){
      int col = wv*32 + nt*16 + l16;
      bfr[nt] = *(const s16x8*)&p.kw2T[((size_t)l*128 + col)*128 + kc*32 + quad*8];
    }
    s16x8 afr[4];
    #pragma unroll
    for (int mt = 0; mt < 4; ++mt)
      afr[mt] = *(const s16x8*)&xs[(mt*16 + l16)*XP + kc*32 + quad*8];
    #pragma unroll
    for (int mt = 0; mt < 4; ++mt)
      #pragma unroll
      for (int nt = 0; nt < 2; ++nt)
        acc[mt][nt] = __builtin_amdgcn_mfma_f32_16x16x32_bf16(afr[mt], bfr[nt], acc[mt][nt], 0, 0, 0);
  }
  float bv[2];
  #pragma unroll
  for (int nt=0;nt<2;++nt) bv[nt] = p.wb[WO_KB2 + l*128 + wv*32 + nt*16 + l16];
  #pragma unroll
  for (int mt = 0; mt < 4; ++mt)
    #pragma unroll
    for (int i = 0; i < 4; ++i){
      int gr = r0 + mt*16 + quad*4 + i;
      if (gr < 5600){
        #pragma unroll
        for (int nt = 0; nt < 2; ++nt)
          p.kpe[(size_t)gr*128 + wv*32 + nt*16 + l16] = f2b(acc[mt][nt][i] + bv[nt]);
      }
    }
}

// saqkv: qpe MLP + sa_qkv projection, 256 threads, LDS 1 KB
DEV void saqkv_block(int n, int t, unsigned char* smem, const P& p, int l, int bf){
  float* hs = (float*)smem;      // 128
  float* xq = hs + 128;          // 128
  if (t < 128){
    float p0 = ld(p.niqp,2*n,bf), p1 = ld(p.niqp,2*n+1,bf);
    float a = fmaf(p0, p.wb[WO_QW1 + l*256 + t], fmaf(p1, p.wb[WO_QW1 + l*256 + 128 + t], p.wb[WO_QB1 + l*128 + t]));
    hs[t] = fmaxf(a, 0.f);
  }
  __syncthreads();
  if (t < 128){
    const float* W = p.wb + WO_QW2 + l*16384;
    float a0 = p.wb[WO_QB2 + l*128 + t], a1 = 0.f, a2 = 0.f, a3 = 0.f;
    #pragma unroll 8
    for (int k = 0; k < 128; k += 4){
      a0 = fmaf(hs[k],   W[k*128 + t],     a0);
      a1 = fmaf(hs[k+1], W[(k+1)*128 + t], a1);
      a2 = fmaf(hs[k+2], W[(k+2)*128 + t], a2);
      a3 = fmaf(hs[k+3], W[(k+3)*128 + t], a3);
    }
    float a = (a0+a1)+(a2+a3);
    p.qpe[(size_t)n*128 + t] = a;
    xq[t] = p.q[(size_t)n*128 + t] + a;
  }
  __syncthreads();
  const float* W = p.wb + WO_SAQKVW + l*49152;
  for (int c = t; c < 384; c += 256){
    float a0 = p.wb[WO_SAQKVB + l*384 + c], a1 = 0.f, a2 = 0.f, a3 = 0.f;
    #pragma unroll 8
    for (int k = 0; k < 128; k += 4){
      a0 = fmaf(xq[k],   W[(long)k*384 + c],     a0);
      a1 = fmaf(xq[k+1], W[(long)(k+1)*384 + c], a1);
      a2 = fmaf(xq[k+2], W[(long)(k+2)*384 + c], a2);
      a3 = fmaf(xq[k+3], W[(long)(k+3)*384 + c], a3);
    }
    p.tmp[(size_t)n*384 + c] = (a0+a1)+(a2+a3);
  }
}

// kv projection MFMA (keys + kpe -> kh/vh), 256 threads, LDS 17.4 KB
DEV void kvproj_block(int b, int t, unsigned char* smem, const P& p, int l){
  constexpr int XP = 136;
  unsigned short* xs = (unsigned short*)smem;
  int r0 = b * 64;
  // vectorized staging: 8 bf16 per iteration (16B loads from keys + kpe)
  for (int idx = t; idx < 64*16; idx += 256){
    int r = idx >> 4, u = idx & 15;
    int gr = r0 + r;
    int v = gr / 5600; int k = gr - v*5600;
    s16x8 kv = *(const s16x8*)&p.keys[(size_t)gr*128 + u*8];
    s16x8 pe = *(const s16x8*)&p.kpe[(size_t)k*128 + u*8];
    s16x8 ov;
    #pragma unroll
    for (int jj=0;jj<8;++jj){
      float a = u2f(((unsigned)(unsigned short)kv[jj])<<16) + u2f(((unsigned)(unsigned short)pe[jj])<<16);
      ov[jj] = (short)f2bu(a);
    }
    *(s16x8*)&xs[r*XP + u*8] = ov;
  }
  int wv = t >> 6;
  int lane = t & 63;
  int l16 = lane & 15, quad = lane >> 4;
  __syncthreads();
  f32x4 acc[4][4];
  #pragma unroll
  for (int mt=0;mt<4;++mt)
    #pragma unroll
    for (int nt=0;nt<4;++nt) acc[mt][nt] = (f32x4){0.f,0.f,0.f,0.f};
  #pragma unroll
  for (int kc = 0; kc < 4; ++kc){
    s16x8 bfr[4];
    #pragma unroll
    for (int nt = 0; nt < 4; ++nt){
      int col = wv*64 + nt*16 + l16;
      bfr[nt] = *(const s16x8*)&p.wkvT[((size_t)l*256 + col)*128 + kc*32 + quad*8];
    }
    s16x8 afr[4];
    #pragma unroll
    for (int mt = 0; mt < 4; ++mt)
      afr[mt] = *(const s16x8*)&xs[(mt*16 + l16)*XP + kc*32 + quad*8];
    #pragma unroll
    for (int mt = 0; mt < 4; ++mt)
      #pragma unroll
      for (int nt = 0; nt < 4; ++nt)
        acc[mt][nt] = __builtin_amdgcn_mfma_f32_16x16x32_bf16(afr[mt], bfr[nt], acc[mt][nt], 0, 0, 0);
  }
  float bv[4];
  bf16* op[4];
  long ntOff[4];
  #pragma unroll
  for (int nt = 0; nt < 4; ++nt){
    int c = wv*64 + nt*16 + l16;
    bv[nt] = p.wb[WO_CAQKVB + l*384 + 128 + c];
    int sel = c >> 7, ch = c & 127;
    int h = ch >> 4, d = ch & 15;
    op[nt] = sel ? p.vh : p.kh;
    ntOff[nt] = (long)h*89600 + d;
  }
  #pragma unroll
  for (int mt = 0; mt < 4; ++mt)
    #pragma unroll
    for (int i = 0; i < 4; ++i){
      int gr = r0 + mt*16 + quad*4 + i;
      int v = gr / 5600; int k = gr - v*5600;
      long rowOff = (long)v*716800 + (long)k*16;
      #pragma unroll
      for (int nt = 0; nt < 4; ++nt)
        op[nt][rowOff + ntOff[nt]] = f2b(acc[mt][nt][i] + bv[nt]);
    }
}

// self-attn + out-proj + LN1 + ca-q projection, 256 threads, LDS 2 KB
DEV void selfattn_block(int n, int t, unsigned char* smem, const P& p, int l){
  float* att  = (float*)smem;    // 128
  float* part = att + 128;       // 256
  float* redw = part + 256;      // 4
  float* xs2  = redw + 4;        // 128
  int h = t >> 5, j = t & 31;
  int vn = p.view[n];
  float4 qA, qB, qC, qD;
  {
    const float4* q4 = (const float4*)(p.tmp + (size_t)n*384 + h*16);
    qA = q4[0]; qB = q4[1]; qC = q4[2]; qD = q4[3];
    qA.x*=0.25f; qA.y*=0.25f; qA.z*=0.25f; qA.w*=0.25f;
    qB.x*=0.25f; qB.y*=0.25f; qB.z*=0.25f; qB.w*=0.25f;
    qC.x*=0.25f; qC.y*=0.25f; qC.z*=0.25f; qC.w*=0.25f;
    qD.x*=0.25f; qD.y*=0.25f; qD.z*=0.25f; qD.w*=0.25f;
  }
  float m = -INFINITY, s = 0.f, o[16];
  #pragma unroll
  for (int d=0; d<16; ++d) o[d]=0.f;
  for (int k = j; k < 200; k += 32){
    float l2;
    if (p.view[k] != vn){ l2 = -INFINITY; }
    else {
      const float4* kr4 = (const float4*)(p.tmp + (size_t)k*384 + 128 + h*16);
      float4 ka = kr4[0], kb = kr4[1], kc = kr4[2], kd = kr4[3];
      float l0 = fmaf(qA.x,ka.x, fmaf(qA.y,ka.y, fmaf(qA.z,ka.z, qA.w*ka.w)));
      float l1 = fmaf(qB.x,kb.x, fmaf(qB.y,kb.y, fmaf(qB.z,kb.z, qB.w*kb.w)));
      float l3 = fmaf(qC.x,kc.x, fmaf(qC.y,kc.y, fmaf(qC.z,kc.z, qC.w*kc.w)));
      float l4 = fmaf(qD.x,kd.x, fmaf(qD.y,kd.y, fmaf(qD.z,kd.z, qD.w*kd.w)));
      l2 = (l0+l1)+(l3+l4);
    }
    float mn = fmaxf(m, l2);
    float ea = (m > -3.0e38f) ? __expf(m - mn) : 0.f;
    float pp = (l2 > -3.0e38f) ? __expf(l2 - mn) : 0.f;
    s = s*ea + pp;
    const float4* vr4 = (const float4*)(p.tmp + (size_t)k*384 + 256 + h*16);
    float4 va = vr4[0], vb = vr4[1], vc = vr4[2], vd = vr4[3];
    o[0]=o[0]*ea+pp*va.x; o[1]=o[1]*ea+pp*va.y; o[2]=o[2]*ea+pp*va.z; o[3]=o[3]*ea+pp*va.w;
    o[4]=o[4]*ea+pp*vb.x; o[5]=o[5]*ea+pp*vb.y; o[6]=o[6]*ea+pp*vb.z; o[7]=o[7]*ea+pp*vb.w;
    o[8]=o[8]*ea+pp*vc.x; o[9]=o[9]*ea+pp*vc.y; o[10]=o[10]*ea+pp*vc.z; o[11]=o[11]*ea+pp*vc.w;
    o[12]=o[12]*ea+pp*vd.x; o[13]=o[13]*ea+pp*vd.y; o[14]=o[14]*ea+pp*vd.z; o[15]=o[15]*ea+pp*vd.w;
    m = mn;
  }
  // max-first merge across 32 lanes
  float M = m;
  #pragma unroll
  for (int off=16; off>=1; off>>=1) M = fmaxf(M, __shfl_xor(M, off));
  float sc = (m > -3.0e38f) ? __expf(m - M) : 0.f;
  s *= sc;
  #pragma unroll
  for (int d=0; d<16; ++d) o[d] *= sc;
  #pragma unroll
  for (int off=16; off>=1; off>>=1){
    s += __shfl_xor(s, off);
    #pragma unroll
    for (int d=0; d<16; ++d) o[d] += __shfl_xor(o[d], off);
  }
  if (j == 0){
    float inv = (s > 0.f) ? 1.f/s : 0.f;
    #pragma unroll
    for (int d=0; d<16; ++d) att[h*16 + d] = o[d]*inv;
  }
  __syncthreads();
  int tc = t & 127, half = t >> 7;
  {
    const float* W = p.wb + WO_SAOW + l*16384;
    int kb = half*64;
    float a0=0.f,a1=0.f,a2=0.f,a3=0.f;
    #pragma unroll
    for (int k = 0; k < 64; k += 4){
      a0 = fmaf(att[kb+k],   W[(kb+k)*128 + tc],   a0);
      a1 = fmaf(att[kb+k+1], W[(kb+k+1)*128 + tc], a1);
      a2 = fmaf(att[kb+k+2], W[(kb+k+2)*128 + tc], a2);
      a3 = fmaf(att[kb+k+3], W[(kb+k+3)*128 + tc], a3);
    }
    part[t] = (a0+a1)+(a2+a3);
  }
  __syncthreads();
  float v = (t<128) ? p.q[(size_t)n*128 + t] + part[t] + part[128+t] + p.wb[WO_SAOB + l*128 + t] : 0.f;
  float sv = wsum64(v);
  if ((t&63)==0) redw[t>>6] = sv;
  __syncthreads();
  float mean = (redw[0]+redw[1]+redw[2]+redw[3]) * (1.f/128.f);
  __syncthreads();
  float d = (t<128)? v-mean : 0.f;
  sv = wsum64(d*d);
  if ((t&63)==0) redw[t>>6] = sv;
  __syncthreads();
  float var = (redw[0]+redw[1]+redw[2]+redw[3]) * (1.f/128.f);
  float r = rsqrtf(var + 1e-5f);
  if (t<128){
    float qn = d*r*p.wb[WO_LN1G + l*128 + t] + p.wb[WO_LN1B + l*128 + t];
    p.q[(size_t)n*128 + t] = qn;
    xs2[t] = qn + p.qpe[(size_t)n*128 + t];
  }
  __syncthreads();
  {
    const float* Wc = p.wb + WO_CAQKVW + l*49152;
    int kb = half*64;
    float a0=0.f,a1=0.f,a2=0.f,a3=0.f;
    #pragma unroll
    for (int k = 0; k < 64; k += 4){
      a0 = fmaf(xs2[kb+k],   Wc[(long)(kb+k)*384 + tc],   a0);
      a1 = fmaf(xs2[kb+k+1], Wc[(long)(kb+k+1)*384 + tc], a1);
      a2 = fmaf(xs2[kb+k+2], Wc[(long)(kb+k+2)*384 + tc], a2);
      a3 = fmaf(xs2[kb+k+3], Wc[(long)(kb+k+3)*384 + tc], a3);
    }
    part[t] = (a0+a1)+(a2+a3);
  }
  __syncthreads();
  if (t<128)
    p.qca[(size_t)n*128 + t] = part[t] + part[128+t] + p.wb[WO_CAQKVB + l*384 + t];
}

// ================= packed launches =================
__global__ __launch_bounds__(256) void k_packA(P p, int l){
  __shared__ __align__(16) unsigned char smem[17920];
  int bf = get_bf(p.ln1g);
  int b = blockIdx.x;
  if (b < 88) kpe_block(b, threadIdx.x, smem, p, l, bf);
  else        saqkv_block(b - 88, threadIdx.x, smem, p, l, bf);
}

__global__ __launch_bounds__(256) void k_packB(P p, int l){
  __shared__ __align__(16) unsigned char smem[17408];
  int b = blockIdx.x;
  if (b < 525) kvproj_block(b, threadIdx.x, smem, p, l);
  else         selfattn_block(b - 525, threadIdx.x, smem, p, l);
}

// ================= cross-attention partial =================
// no-LDS, query-PAIRED: each 32-lane group processes 2 consecutive queries,
// amortizing K/V loads + bf16 unpacks across both; independent softmax chains
// interleave for latency hiding. NSLICE=3, contiguous pair assignment.
__global__ __launch_bounds__(256) void k_cross_part(P p){
  int ch = blockIdx.x, h = blockIdx.y;
  int v = blockIdx.z / NSLICE, sl = blockIdx.z - v*NSLICE;
  int t = threadIdx.x;
  int k0 = ch*CK;
  int nq = p.qlp[v];
  const int* ql = p.qlp + 8 + v*200;
  int g = t >> 5, j = t & 31;
  const uint4* ks = (const uint4*)(p.kh + ((size_t)(v*8 + h)*5600 + k0)*16);
  const uint4* vs = (const uint4*)(p.vh + ((size_t)(v*8 + h)*5600 + k0)*16);
  const float2* fp = ((const float2*)p.fpos) + k0;
  for (int base = (sl*8 + g)*2; base < nq; base += 8*NSLICE*2){
    bool has1 = (base + 1 < nq);
    int n0 = ql[base];
    int n1 = has1 ? ql[base+1] : n0;
    float cx0 = p.ctr[2*n0], cy0 = p.ctr[2*n0+1], is20 = p.sig2[n0];
    float cx1 = p.ctr[2*n1], cy1 = p.ctr[2*n1+1], is21 = p.sig2[n1];
    const float4* q40 = (const float4*)(p.qca + (size_t)n0*128 + h*16);
    const float4* q41 = (const float4*)(p.qca + (size_t)n1*128 + h*16);
    float4 qA0=q40[0], qB0=q40[1], qC0=q40[2], qD0=q40[3];
    float4 qA1=q41[0], qB1=q41[1], qC1=q41[2], qD1=q41[3];
    qA0.x*=0.25f;qA0.y*=0.25f;qA0.z*=0.25f;qA0.w*=0.25f;
    qB0.x*=0.25f;qB0.y*=0.25f;qB0.z*=0.25f;qB0.w*=0.25f;
    qC0.x*=0.25f;qC0.y*=0.25f;qC0.z*=0.25f;qC0.w*=0.25f;
    qD0.x*=0.25f;qD0.y*=0.25f;qD0.z*=0.25f;qD0.w*=0.25f;
    qA1.x*=0.25f;qA1.y*=0.25f;qA1.z*=0.25f;qA1.w*=0.25f;
    qB1.x*=0.25f;qB1.y*=0.25f;qB1.z*=0.25f;qB1.w*=0.25f;
    qC1.x*=0.25f;qC1.y*=0.25f;qC1.z*=0.25f;qC1.w*=0.25f;
    qD1.x*=0.25f;qD1.y*=0.25f;qD1.z*=0.25f;qD1.w*=0.25f;
    // gaussian gates for both queries (5 keys each)
    float gg0[5], gg1[5];
    #pragma unroll
    for (int i = 0; i < 5; ++i){
      float2 pxy = fp[i*32 + j];
      float dx0 = cx0 - pxy.x, dy0 = cy0 - pxy.y;
      gg0[i] = -(dx0*dx0 + dy0*dy0) * is20;
      float dx1 = cx1 - pxy.x, dy1 = cy1 - pxy.y;
      gg1[i] = -(dx1*dx1 + dy1*dy1) * is21;
    }
    // logits: load+unpack each K row ONCE, dot against both queries
    float lg0[5], lg1[5];
    #pragma unroll
    for (int i = 0; i < 5; ++i){
      bool p0ok = (gg0[i] >= LOG_EPS);
      bool p1ok = has1 && (gg1[i] >= LOG_EPS);
      lg0[i] = -INFINITY; lg1[i] = -INFINITY;
      if (!(p0ok || p1ok)) continue;
      int key = i*32 + j;
      uint4 a = ks[key*2], b = ks[key*2+1];
      float kf[16];
      unpack2(a.x, kf);    unpack2(a.y, kf+2);  unpack2(a.z, kf+4);  unpack2(a.w, kf+6);
      unpack2(b.x, kf+8);  unpack2(b.y, kf+10); unpack2(b.z, kf+12); unpack2(b.w, kf+14);
      if (p0ok){
        float l0 = fmaf(qA0.x,kf[0], fmaf(qA0.y,kf[1], fmaf(qA0.z,kf[2],  qA0.w*kf[3])));
        float l1 = fmaf(qB0.x,kf[4], fmaf(qB0.y,kf[5], fmaf(qB0.z,kf[6],  qB0.w*kf[7])));
        float l3 = fmaf(qC0.x,kf[8], fmaf(qC0.y,kf[9], fmaf(qC0.z,kf[10], qC0.w*kf[11])));
        float l4 = fmaf(qD0.x,kf[12],fmaf(qD0.y,kf[13],fmaf(qD0.z,kf[14], qD0.w*kf[15])));
        lg0[i] = gg0[i] + ((l0+l1)+(l3+l4));
      }
      if (p1ok){
        float l0 = fmaf(qA1.x,kf[0], fmaf(qA1.y,kf[1], fmaf(qA1.z,kf[2],  qA1.w*kf[3])));
        float l1 = fmaf(qB1.x,kf[4], fmaf(qB1.y,kf[5], fmaf(qB1.z,kf[6],  qB1.w*kf[7])));
        float l3 = fmaf(qC1.x,kf[8], fmaf(qC1.y,kf[9], fmaf(qC1.z,kf[10], qC1.w*kf[11])));
        float l4 = fmaf(qD1.x,kf[12],fmaf(qD1.y,kf[13],fmaf(qD1.z,kf[14], qD1.w*kf[15])));
        lg1[i] = gg1[i] + ((l0+l1)+(l3+l4));
      }
    }
    // group max (both chains independent)
    float m0 = fmaxf(fmaxf(fmaxf(lg0[0],lg0[1]), fmaxf(lg0[2],lg0[3])), lg0[4]);
    float m1 = fmaxf(fmaxf(fmaxf(lg1[0],lg1[1]), fmaxf(lg1[2],lg1[3])), lg1[4]);
    #pragma unroll
    for (int off=16; off>=1; off>>=1){
      m0 = fmaxf(m0, __shfl_xor(m0, off));
      m1 = fmaxf(m1, __shfl_xor(m1, off));
    }
    float pr0[5], pr1[5], s0 = 0.f, s1 = 0.f;
    #pragma unroll
    for (int i = 0; i < 5; ++i){
      pr0[i] = (lg0[i] > -3.0e38f) ? __expf(lg0[i] - m0) : 0.f;
      s0 += pr0[i];
      pr1[i] = (lg1[i] > -3.0e38f) ? __expf(lg1[i] - m1) : 0.f;
      s1 += pr1[i];
    }
    // PV: load+unpack each V row ONCE, accumulate both
    float o0[16], o1[16];
    #pragma unroll
    for (int d=0; d<16; ++d){ o0[d] = 0.f; o1[d] = 0.f; }
    #pragma unroll
    for (int i = 0; i < 5; ++i){
      bool need = (pr0[i] > 0.f) || (pr1[i] > 0.f);
      if (!need) continue;
      int key = i*32 + j;
      uint4 a = vs[key*2], b = vs[key*2+1];
      float vf[16];
      unpack2(a.x, vf);    unpack2(a.y, vf+2);  unpack2(a.z, vf+4);  unpack2(a.w, vf+6);
      unpack2(b.x, vf+8);  unpack2(b.y, vf+10); unpack2(b.z, vf+12); unpack2(b.w, vf+14);
      float w0 = pr0[i], w1 = pr1[i];
      #pragma unroll
      for (int d=0; d<16; ++d){
        o0[d] = fmaf(w0, vf[d], o0[d]);
        o1[d] = fmaf(w1, vf[d], o1[d]);
      }
    }
    // group sum (both chains interleaved)
    #pragma unroll
    for (int off=16; off>=1; off>>=1){
      s0 += __shfl_xor(s0, off);
      s1 += __shfl_xor(s1, off);
      #pragma unroll
      for (int d=0; d<16; ++d){
        o0[d] += __shfl_xor(o0[d], off);
        o1[d] += __shfl_xor(o1[d], off);
      }
    }
    if (j == 0){
      int idx0 = (n0*NC + ch)*8 + h;
      p.pm[idx0] = m0; p.ps[idx0] = s0;
      float4* o4 = (float4*)(p.po + (size_t)idx0*16);
      o4[0] = make_float4(o0[0],o0[1],o0[2],o0[3]);
      o4[1] = make_float4(o0[4],o0[5],o0[6],o0[7]);
      o4[2] = make_float4(o0[8],o0[9],o0[10],o0[11]);
      o4[3] = make_float4(o0[12],o0[13],o0[14],o0[15]);
      if (has1){
        int idx1 = (n1*NC + ch)*8 + h;
        p.pm[idx1] = m1; p.ps[idx1] = s1;
        float4* o41 = (float4*)(p.po + (size_t)idx1*16);
        o41[0] = make_float4(o1[0],o1[1],o1[2],o1[3]);
        o41[1] = make_float4(o1[4],o1[5],o1[6],o1[7]);
        o41[2] = make_float4(o1[8],o1[9],o1[10],o1[11]);
        o41[3] = make_float4(o1[12],o1[13],o1[14],o1[15]);
      }
    }
  }
}

// ================= tail =================
__global__ __launch_bounds__(256) void k_tail(P p, int l){
  __shared__ float att[128];
  __shared__ float sm[2][128], ss[2][128], so[2][128];
  __shared__ float part[256];
  __shared__ float redw[4];
  __shared__ float xs[128];
  __shared__ float hs[256];
  __shared__ float redw6[24];
  __shared__ float bbv[8];
  int bf = get_bf(p.ln1g);
  int n = blockIdx.x, t = threadIdx.x;
  long outOff = (l==0) ? 45200L : 46400L;
  int last = (l==1);
  int tc = t & 127, half = t >> 7;
  {
    // batched combine: load all chunk triples, then max tree + independent exps
    int h = tc >> 4, d = tc & 15;
    int c0 = half ? 18 : 0, c1 = half ? NC : 18;
    float pmv[18], psv[18], pov[18];
    #pragma unroll
    for (int i = 0; i < 18; ++i){
      int c = c0 + i;
      bool ok = (c < c1);
      int cc = ok ? c : c0;
      int idx = (n*NC + cc)*8 + h;
      pmv[i] = ok ? p.pm[idx] : -INFINITY;
      psv[i] = ok ? p.ps[idx] : 0.f;
      pov[i] = ok ? p.po[(size_t)idx*16 + d] : 0.f;
    }
    float m = pmv[0];
    #pragma unroll
    for (int i = 1; i < 18; ++i) m = fmaxf(m, pmv[i]);
    float s = 0.f, o = 0.f;
    #pragma unroll
    for (int i = 0; i < 18; ++i){
      float e = (pmv[i] > -3.0e38f) ? __expf(pmv[i] - m) : 0.f;
      s = fmaf(psv[i], e, s);
      o = fmaf(pov[i], e, o);
    }
    sm[half][tc]=m; ss[half][tc]=s; so[half][tc]=o;
  }
  __syncthreads();
  if (t < 128){
    float m1=sm[0][t], m2=sm[1][t];
    float mn=fmaxf(m1,m2);
    float e1=(m1>-3.0e38f)?__expf(m1-mn):0.f, e2=(m2>-3.0e38f)?__expf(m2-mn):0.f;
    float s = ss[0][t]*e1 + ss[1][t]*e2;
    float o = so[0][t]*e1 + so[1][t]*e2;
    att[t] = (s>0.f)? o/s : 0.f;
  }
  __syncthreads();
  {
    const float* W = p.wb + WO_CAOW + l*16384;
    int kb = half*64;
    float a0=0.f,a1=0.f,a2=0.f,a3=0.f;
    #pragma unroll
    for (int k = 0; k < 64; k += 4){
      a0 = fmaf(att[kb+k],   W[(kb+k)*128 + tc],   a0);
      a1 = fmaf(att[kb+k+1], W[(kb+k+1)*128 + tc], a1);
      a2 = fmaf(att[kb+k+2], W[(kb+k+2)*128 + tc], a2);
      a3 = fmaf(att[kb+k+3], W[(kb+k+3)*128 + tc], a3);
    }
    part[t] = (a0+a1)+(a2+a3);
  }
  __syncthreads();
  float v = (t<128) ? p.q[(size_t)n*128 + t] + part[t] + part[128+t] + p.wb[WO_CAOB + l*128 + t] : 0.f;
  float sv = wsum64(v);
  if ((t&63)==0) redw[t>>6] = sv;
  __syncthreads();
  float mean = (redw[0]+redw[1]+redw[2]+redw[3]) * (1.f/128.f);
  __syncthreads();
  float d = (t<128)? v-mean : 0.f;
  sv = wsum64(d*d);
  if ((t&63)==0) redw[t>>6] = sv;
  __syncthreads();
  float var = (redw[0]+redw[1]+redw[2]+redw[3]) * (1.f/128.f);
  float r = rsqrtf(var + 1e-5f);
  if (t<128) xs[t] = d*r*p.wb[WO_LN2G + l*128 + t] + p.wb[WO_LN2B + l*128 + t];
  __syncthreads();
  {
    const float* W = p.wb + WO_FW1 + l*32768;
    float a0 = p.wb[WO_FB1 + l*256 + t], a1=0.f, a2=0.f, a3=0.f;
    #pragma unroll 8
    for (int k = 0; k < 128; k += 4){
      a0 = fmaf(xs[k],   W[k*256 + t],     a0);
      a1 = fmaf(xs[k+1], W[(k+1)*256 + t], a1);
      a2 = fmaf(xs[k+2], W[(k+2)*256 + t], a2);
      a3 = fmaf(xs[k+3], W[(k+3)*256 + t], a3);
    }
    hs[t] = fmaxf((a0+a1)+(a2+a3), 0.f);
  }
  __syncthreads();
  {
    const float* W = p.wb + WO_FW2 + l*32768;
    int kb = half*128;
    float a0=0.f,a1=0.f,a2=0.f,a3=0.f;
    #pragma unroll 8
    for (int k = 0; k < 128; k += 4){
      a0 = fmaf(hs[kb+k],   W[(kb+k)*128 + tc],   a0);
      a1 = fmaf(hs[kb+k+1], W[(kb+k+1)*128 + tc], a1);
      a2 = fmaf(hs[kb+k+2], W[(kb+k+2)*128 + tc], a2);
      a3 = fmaf(hs[kb+k+3], W[(kb+k+3)*128 + tc], a3);
    }
    part[t] = (a0+a1)+(a2+a3);
  }
  __syncthreads();
  v = (t<128) ? xs[t] + part[t] + part[128+t] + p.wb[WO_FB2 + l*128 + t] : 0.f;
  sv = wsum64(v);
  if ((t&63)==0) redw[t>>6] = sv;
  __syncthreads();
  mean = (redw[0]+redw[1]+redw[2]+redw[3]) * (1.f/128.f);
  __syncthreads();
  d = (t<128)? v-mean : 0.f;
  sv = wsum64(d*d);
  if ((t&63)==0) redw[t>>6] = sv;
  __syncthreads();
  var = (redw[0]+redw[1]+redw[2]+redw[3]) * (1.f/128.f);
  r = rsqrtf(var + 1e-5f);
  if (t<128){
    float q3 = d*r*p.wb[WO_LN3G + l*128 + t] + p.wb[WO_LN3B + l*128 + t];
    p.q[(size_t)n*128 + t] = q3;
    xs[t] = q3;
    if (last) st(p.out, (long)t*200 + n, q3, bf);
  }
  __syncthreads();
  {
    const float* W = p.wb + WO_PW1;
    int kb = half*64;
    float a0=0.f,a1=0.f,a2=0.f,a3=0.f;
    #pragma unroll
    for (int k = 0; k < 64; k += 4){
      a0 = fmaf(xs[kb+k],   W[(kb+k)*128 + tc],   a0);
      a1 = fmaf(xs[kb+k+1], W[(kb+k+1)*128 + tc], a1);
      a2 = fmaf(xs[kb+k+2], W[(kb+k+2)*128 + tc], a2);
      a3 = fmaf(xs[kb+k+3], W[(kb+k+3)*128 + tc], a3);
    }
    part[t] = (a0+a1)+(a2+a3);
  }
  __syncthreads();
  {
    float x = (t<128) ? fmaxf(part[t] + part[128+t] + p.wb[WO_PB1 + t], 0.f) : 0.f;
    #pragma unroll
    for (int c=0;c<6;++c){
      float val = wsum64((t<128) ? x * p.wb[WO_PW2 + t*6 + c] : 0.f);
      if ((t&63)==0) redw6[(t>>6)*6 + c] = val;
    }
  }
  __syncthreads();
  if (t < 6){
    float raw = redw6[t] + redw6[6+t] + redw6[12+t] + redw6[18+t] + p.wb[WO_PB2 + t];
    if (t < 2) raw += ld(p.niqp, 2*n + t, bf);
    float svv = sigm(raw);
    st(p.out, outOff + n*6 + t, svv, bf);
    bbv[t] = svv;
  }
  __syncthreads();
  if (t == 0){
    float dxv = sigm(bbv[2]) * IMGX;
    float dyv = sigm(bbv[3]) * IMGY;
    float rad = ceilf(sqrtf(dxv*dxv + dyv*dyv) * 0.5f);
    float sg = (rad*2.f + 1.f) * (1.f/6.f);
    p.sig2[n] = 1.f/(2.f*sg*sg);
  }
}

// ================= launch =================
extern "C" void kernel_launch(void* const* d_in, const int* in_sizes, int n_in,
                              void* d_out, int out_size, void* d_ws, size_t ws_size,
                              hipStream_t stream){
  const void* iqf   = d_in[0];
  const void* niqp  = d_in[1];
  const void* iff   = d_in[2];
  const void* nifp  = d_in[3];
  const void* l2i   = d_in[4];
  const int*  view  = (const int*)d_in[5];
  const void* ln1_g = d_in[14];

  float* fw = (float*)d_ws;
  int*   qlp  = (int*)(fw + OFF_QL);
  float* wb   = fw + OFF_WB;
  bf16* bw   = (bf16*)((char*)d_ws + F_TOTAL*sizeof(float));
  bf16* wkvT_m = bw + B_WKVT;
  bf16* kw2T_m = bw + B_KW2T;

  P p;
  p.nifp = nifp; p.iff = iff; p.niqp = niqp; p.ln1g = ln1_g;
  p.view = view; p.qlp = qlp;
  p.wb = wb;
  p.q = fw + OFF_Q; p.qpe = fw + OFF_QPE; p.qca = fw + OFF_QCA; p.tmp = fw + OFF_TMP;
  p.pm = fw + OFF_PM; p.ps = fw + OFF_PS; p.po = fw + OFF_PO;
  p.fpos = fw + OFF_FPOS; p.ctr = fw + OFF_CTR; p.sig2 = fw + OFF_SIG;
  p.kw2T = kw2T_m; p.wkvT = wkvT_m; p.keys = bw + B_KEYS;
  p.kh = bw + B_KH; p.vh = bw + B_VH; p.kpe = bw + B_KPE;
  p.out = d_out;

  CvtArgs ca;
  ca.s[0]  = {d_in[6],  WO_SAQKVW, 98304};
  ca.s[1]  = {d_in[7],  WO_SAQKVB, 768};
  ca.s[2]  = {d_in[8],  WO_SAOW,   32768};
  ca.s[3]  = {d_in[9],  WO_SAOB,   256};
  ca.s[4]  = {d_in[10], WO_CAQKVW, 98304};
  ca.s[5]  = {d_in[11], WO_CAQKVB, 768};
  ca.s[6]  = {d_in[12], WO_CAOW,   32768};
  ca.s[7]  = {d_in[13], WO_CAOB,   256};
  ca.s[8]  = {d_in[14], WO_LN1G,   256};
  ca.s[9]  = {d_in[15], WO_LN1B,   256};
  ca.s[10] = {d_in[16], WO_LN2G,   256};
  ca.s[11] = {d_in[17], WO_LN2B,   256};
  ca.s[12] = {d_in[18], WO_LN3G,   256};
  ca.s[13] = {d_in[19], WO_LN3B,   256};
  ca.s[14] = {d_in[20], WO_FW1,    65536};
  ca.s[15] = {d_in[21], WO_FB1,    512};
  ca.s[16] = {d_in[22], WO_FW2,    65536};
  ca.s[17] = {d_in[23], WO_FB2,    256};
  ca.s[18] = {d_in[24], WO_QW1,    512};
  ca.s[19] = {d_in[25], WO_QB1,    256};
  ca.s[20] = {d_in[26], WO_QW2,    32768};
  ca.s[21] = {d_in[27], WO_QB2,    256};
  ca.s[22] = {d_in[28], WO_KW1,    512};
  ca.s[23] = {d_in[29], WO_KB1,    256};
  ca.s[24] = {d_in[31], WO_KB2,    256};
  ca.s[25] = {d_in[32], WO_PW1,    16384};
  ca.s[26] = {d_in[33], WO_PB1,    128};
  ca.s[27] = {d_in[34], WO_PW2,    768};
  ca.s[28] = {d_in[35], WO_PB2,    6};

  k_cvt<<<dim3(30,8), 256, 0, stream>>>(ca, wb, qlp, view, ln1_g);
  k_wT<<<dim3(384,2), 128, 0, stream>>>(d_in[10], d_in[30], wkvT_m, kw2T_m, ln1_g);
  k_transpose<<<dim3(175,4,6), dim3(32,8), 0, stream>>>(iff, bw + B_KEYS, ln1_g);
  k_prep2<<<200, 128, 0, stream>>>(niqp, l2i, nifp, view, iqf, p.ctr, p.fpos, p.q, wb, p.sig2, d_out, ln1_g);

  for (int l = 0; l < 2; ++l){
    k_packA<<<288, 256, 0, stream>>>(p, l);
    k_packB<<<725, 256, 0, stream>>>(p, l);
    k_cross_part<<<dim3(NC,8,6*NSLICE), 256, 0, stream>>>(p);
    k_tail<<<200, 256, 0, stream>>>(p, l);
  }
}

// Round 9
// 360.454 us; speedup vs baseline: 1.0604x; 1.0604x over previous
//
#include <hip/hip_runtime.h>
#include <hip/hip_bf16.h>
#include <cstdint>
#include <cstddef>

using bf16 = __hip_bfloat16;
#define DEV __device__ __forceinline__

typedef short s16x8 __attribute__((ext_vector_type(8)));
typedef float f32x4 __attribute__((ext_vector_type(4)));

DEV float b2f(bf16 x){ return __bfloat162float(x); }
DEV bf16  f2b(float x){ return __float2bfloat16(x); }
DEV float u2f(unsigned u){ union{unsigned u; float f;} c; c.u=u; return c.f; }
DEV unsigned f2u(float f){ union{float f; unsigned u;} c; c.f=f; return c.u; }
DEV unsigned short f2bu(float f){ unsigned u = f2u(f); u += 0x7FFFu + ((u>>16)&1u); return (unsigned short)(u>>16); }
DEV float sigm(float x){ return 1.f/(1.f+__expf(-x)); }
DEV int get_bf(const void* ln1g){ return ((*(const unsigned*)ln1g) & 0xFFFFu) == 0x3F80u; }

DEV float ld(const void* p, long i, int bf){
  return bf ? b2f(((const bf16*)p)[i]) : ((const float*)p)[i];
}
DEV void st(void* p, long i, float v, int bf){
  if (bf) ((bf16*)p)[i] = f2b(v); else ((float*)p)[i] = v;
}

constexpr float IMGX = 100.0f;
constexpr float IMGY = 56.0f;
constexpr float LOG_EPS = -15.942385f;
constexpr float BIN = 53.0f/1056.0f;
constexpr int NC = 35;
constexpr int CK = 160;
constexpr int NSLICE = 5;

// ---- fp32 weight buffer offsets (floats) ----
constexpr int WO_SAQKVW = 0;
constexpr int WO_SAQKVB = 98304;
constexpr int WO_SAOW   = 99072;
constexpr int WO_SAOB   = 131840;
constexpr int WO_CAQKVW = 132096;
constexpr int WO_CAQKVB = 230400;
constexpr int WO_CAOW   = 231168;
constexpr int WO_CAOB   = 263936;
constexpr int WO_LN1G   = 264192;
constexpr int WO_LN1B   = 264448;
constexpr int WO_LN2G   = 264704;
constexpr int WO_LN2B   = 264960;
constexpr int WO_LN3G   = 265216;
constexpr int WO_LN3B   = 265472;
constexpr int WO_FW1    = 265728;
constexpr int WO_FB1    = 331264;
constexpr int WO_FW2    = 331776;
constexpr int WO_FB2    = 397312;
constexpr int WO_QW1    = 397568;
constexpr int WO_QB1    = 398080;
constexpr int WO_QW2    = 398336;
constexpr int WO_QB2    = 431104;
constexpr int WO_KW1    = 431360;
constexpr int WO_KB1    = 431872;
constexpr int WO_KB2    = 432128;
constexpr int WO_PW1    = 432384;
constexpr int WO_PB1    = 448768;
constexpr int WO_PW2    = 448896;
constexpr int WO_PB2    = 449664;
constexpr int W_TOTAL   = 449680;

// ---- workspace layout (floats) ----
constexpr size_t OFF_Q    = 0;
constexpr size_t OFF_QPE  = 25600;
constexpr size_t OFF_QCA  = 51200;
constexpr size_t OFF_TMP  = 76800;
constexpr size_t OFF_PM   = 153600;
constexpr size_t OFF_PS   = 209600;
constexpr size_t OFF_PO   = 265600;
constexpr size_t OFF_FPOS = 1161600;
constexpr size_t OFF_CTR  = 1172800;
constexpr size_t OFF_SIG  = 1173200;
constexpr size_t OFF_QL   = 1173400;
constexpr size_t OFF_WB   = 1174624;
constexpr size_t F_TOTAL  = OFF_WB + W_TOTAL;
// bf16 region (elements):
constexpr size_t B_KEYS = 0;          // 33600*128
constexpr size_t B_KH   = 4300800;
constexpr size_t B_VH   = 8601600;
constexpr size_t B_KPE  = 12902400;   // 5600*128
constexpr size_t B_WKVT = 13619200;   // 2*256*128
constexpr size_t B_KW2T = 13684736;   // 2*128*128

DEV void unpack2(unsigned u, float* f){ f[0]=u2f(u<<16); f[1]=u2f(u&0xffff0000u); }

DEV float wsum64(float v){
  #pragma unroll
  for (int off=32; off; off>>=1) v += __shfl_xor(v, off);
  return v;
}

// ================= params bundle =================
struct P {
  const void *nifp, *iff, *niqp, *ln1g;
  const int *view, *qlp;
  const float *wb;
  float *q, *qpe, *qca, *tmp, *pm, *ps, *po, *fpos, *ctr, *sig2;
  const bf16 *kw2T, *wkvT, *keys;
  bf16 *kh, *vh, *kpe;
  void *out;
};

// ================= weight conversion + qlist =================
struct Seg { const void* src; int off; int n; };
struct CvtArgs { Seg s[29]; };

__global__ void k_cvt(CvtArgs a, float* dst, int* qlp, const int* view, const void* ln1g){
  if (blockIdx.x == 29){
    int t = threadIdx.x;
    if (blockIdx.y == 0 && t < 6){
      int cnt = 0;
      for (int i = 0; i < 200; ++i)
        if (view[i] == t) qlp[8 + t*200 + cnt++] = i;
      qlp[t] = cnt;
    }
    return;
  }
  int bf = get_bf(ln1g);
  Seg sg = a.s[blockIdx.x];
  for (int i = blockIdx.y*blockDim.x + threadIdx.x; i < sg.n; i += gridDim.y*blockDim.x)
    dst[sg.off + i] = ld(sg.src, i, bf);
}

__global__ __launch_bounds__(128) void k_wT(const void* __restrict__ caw, const void* __restrict__ kw2,
                                            bf16* __restrict__ wkvT, bf16* __restrict__ kw2T,
                                            const void* __restrict__ ln1g){
  int bf = get_bf(ln1g);
  int c = blockIdx.x, l = blockIdx.y, k = threadIdx.x;
  if (c < 256){
    wkvT[((size_t)l*256 + c)*128 + k] = f2b(ld(caw, (long)l*49152 + (long)k*384 + 128 + c, bf));
  } else {
    int cc = c - 256;
    kw2T[((size_t)l*128 + cc)*128 + k] = f2b(ld(kw2, (long)l*16384 + (long)k*128 + cc, bf));
  }
}

// ================= transpose iff -> keys (row-major [v*5600+k][128]) =================
__global__ void k_transpose(const void* __restrict__ iff, bf16* __restrict__ keys,
                            const void* __restrict__ ln1g){
  __shared__ float t[32][33];
  int bf = get_bf(ln1g);
  int k0 = blockIdx.x*32, c0 = blockIdx.y*32, v = blockIdx.z;
  int tx = threadIdx.x, ty = threadIdx.y;
  #pragma unroll
  for (int i=0;i<4;++i){
    int c = c0 + ty + i*8;
    t[ty+i*8][tx] = ld(iff, (long)(v*128 + c)*5600 + k0 + tx, bf);
  }
  __syncthreads();
  #pragma unroll
  for (int i=0;i<4;++i){
    int k = k0 + ty + i*8;
    keys[(size_t)(v*5600 + k)*128 + c0 + tx] = f2b(t[tx][ty+i*8]);
  }
}

// ================= prep2: centers/inverse/pos3d + q-init + pred0 sigma + fpos =================
__global__ __launch_bounds__(128) void k_prep2(
    const void* __restrict__ niqp, const void* __restrict__ l2i, const void* __restrict__ nifp,
    const int* __restrict__ view, const void* __restrict__ iqf,
    float* __restrict__ ctr, float* __restrict__ fpos, float* __restrict__ q,
    const float* __restrict__ wb, float* __restrict__ is2p,
    void* __restrict__ out, const void* __restrict__ ln1g){
  __shared__ float M[16];
  __shared__ float cs[2];
  __shared__ float xs[128];
  __shared__ float redw6[12];
  __shared__ float bbv[8];
  int bf = get_bf(ln1g);
  int n = blockIdx.x, t = threadIdx.x;
  if (t < 28){
    int k = n*28 + t;
    fpos[2*k]   = sigm(ld(nifp,2*k,bf))*IMGX - 0.5f;
    fpos[2*k+1] = sigm(ld(nifp,2*k+1,bf))*IMGY - 0.5f;
  }
  float xv = ld(iqf, (long)t*200 + n, bf);
  q[(size_t)n*128 + t] = xv;
  xs[t] = xv;
  if (t == 0){
    float p0 = ld(niqp,2*n,bf), p1 = ld(niqp,2*n+1,bf);
    float cx = sigm(p0)*IMGX, cy = sigm(p1)*IMGY;
    ctr[2*n] = cx; ctr[2*n+1] = cy;
    cs[0] = cx; cs[1] = cy;
    st(out, 25600 + 2*n,   p0, bf);
    st(out, 25600 + 2*n+1, p1, bf);
    int v = view[n];
    float a[4][8];
    for (int i=0;i<4;++i)
      for (int jj=0;jj<4;++jj){ a[i][jj] = ld(l2i, v*16+i*4+jj, bf); a[i][4+jj] = (i==jj)?1.f:0.f; }
    for (int col=0; col<4; ++col){
      int p = col; float best = fabsf(a[col][col]);
      for (int r=col+1;r<4;++r){ float tt=fabsf(a[r][col]); if (tt>best){best=tt;p=r;} }
      if (p!=col) for (int jj=0;jj<8;++jj){ float tt=a[col][jj]; a[col][jj]=a[p][jj]; a[p][jj]=tt; }
      float inv = 1.f/a[col][col];
      for (int jj=0;jj<8;++jj) a[col][jj]*=inv;
      for (int r=0;r<4;++r){
        if (r==col) continue;
        float f = a[r][col];
        for (int jj=0;jj<8;++jj) a[r][jj] -= f*a[col][jj];
      }
    }
    for (int i=0;i<4;++i) for (int jj=0;jj<4;++jj) M[i*4+jj] = a[i][4+jj];
  }
  __syncthreads();
  if (t < 32){
    int d = t;
    float px = cs[0]*8.f, py = cs[1]*8.f;
    float dep = 1.f + BIN * (float)d * (float)(d+1);
    float x = px*dep, y = py*dep;
    #pragma unroll
    for (int i=0;i<3;++i){
      float val = M[i*4]*x + M[i*4+1]*y + M[i*4+2]*dep + M[i*4+3];
      st(out, 26000 + n*96 + d*3 + i, val, bf);
    }
  }
  float a0 = wb[WO_PB1 + t], a1 = 0.f, a2 = 0.f, a3 = 0.f;
  const float* W = wb + WO_PW1;
  #pragma unroll 8
  for (int k = 0; k < 128; k += 4){
    a0 = fmaf(xs[k],   W[k*128 + t],     a0);
    a1 = fmaf(xs[k+1], W[(k+1)*128 + t], a1);
    a2 = fmaf(xs[k+2], W[(k+2)*128 + t], a2);
    a3 = fmaf(xs[k+3], W[(k+3)*128 + t], a3);
  }
  float x = fmaxf((a0+a1)+(a2+a3), 0.f);
  #pragma unroll
  for (int c=0;c<6;++c){
    float val = wsum64(x * wb[WO_PW2 + t*6 + c]);
    if ((t&63)==0) redw6[(t>>6)*6 + c] = val;
  }
  __syncthreads();
  if (t < 6) bbv[t] = redw6[t] + redw6[6+t] + wb[WO_PB2 + t];
  __syncthreads();
  if (t == 0){
    float dxv = sigm(bbv[2]) * IMGX;
    float dyv = sigm(bbv[3]) * IMGY;
    float rad = ceilf(sqrtf(dxv*dxv + dyv*dyv) * 0.5f);
    float sg = (rad*2.f + 1.f) * (1.f/6.f);
    is2p[n] = 1.f/(2.f*sg*sg);
  }
}

// ================= stage bodies =================

// kpe MFMA (writes bf16 kpe), 256 threads, LDS 17.9 KB
DEV void kpe_block(int b, int t, unsigned char* smem, const P& p, int l, int bf){
  constexpr int XP = 136;
  unsigned short* xs = (unsigned short*)smem;
  float2* pr = (float2*)(xs + 64*XP);
  int r0 = b * 64;
  if (t < 64){
    int k = r0 + t; if (k > 5599) k = 5599;
    pr[t] = make_float2(ld(p.nifp,2*k,bf), ld(p.nifp,2*k+1,bf));
  }
  __syncthreads();
  const float* w1 = p.wb + WO_KW1 + l*256;
  const float* b1 = p.wb + WO_KB1 + l*128;
  for (int idx = t; idx < 64*64; idx += 256){
    int r = idx >> 6, c2 = (idx & 63)*2;
    float2 pp = pr[r];
    #pragma unroll
    for (int u=0;u<2;++u){
      int c = c2+u;
      float a = fmaf(pp.x, w1[c], fmaf(pp.y, w1[128+c], b1[c]));
      xs[r*XP + c] = f2bu(fmaxf(a, 0.f));
    }
  }
  int wv = t >> 6;
  int lane = t & 63;
  int l16 = lane & 15, quad = lane >> 4;
  __syncthreads();
  f32x4 acc[4][2];
  #pragma unroll
  for (int mt=0;mt<4;++mt)
    #pragma unroll
    for (int nt=0;nt<2;++nt) acc[mt][nt] = (f32x4){0.f,0.f,0.f,0.f};
  #pragma unroll
  for (int kc = 0; kc < 4; ++kc){
    s16x8 bfr[2];
    #pragma unroll
    for (int nt = 0; nt < 2; ++nt){
      int col = wv*32 + nt*16 + l16;
      bfr[nt] = *(const s16x8*)&p.kw2T[((size_t)l*128 + col)*128 + kc*32 + quad*8];
    }
    s16x8 afr[4];
    #pragma unroll
    for (int mt = 0; mt < 4; ++mt)
      afr[mt] = *(const s16x8*)&xs[(mt*16 + l16)*XP + kc*32 + quad*8];
    #pragma unroll
    for (int mt = 0; mt < 4; ++mt)
      #pragma unroll
      for (int nt = 0; nt < 2; ++nt)
        acc[mt][nt] = __builtin_amdgcn_mfma_f32_16x16x32_bf16(afr[mt], bfr[nt], acc[mt][nt], 0, 0, 0);
  }
  float bv[2];
  #pragma unroll
  for (int nt=0;nt<2;++nt) bv[nt] = p.wb[WO_KB2 + l*128 + wv*32 + nt*16 + l16];
  #pragma unroll
  for (int mt = 0; mt < 4; ++mt)
    #pragma unroll
    for (int i = 0; i < 4; ++i){
      int gr = r0 + mt*16 + quad*4 + i;
      if (gr < 5600){
        #pragma unroll
        for (int nt = 0; nt < 2; ++nt)
          p.kpe[(size_t)gr*128 + wv*32 + nt*16 + l16] = f2b(acc[mt][nt][i] + bv[nt]);
      }
    }
}

// saqkv: qpe MLP + sa_qkv projection, 256 threads, LDS 1 KB
DEV void saqkv_block(int n, int t, unsigned char* smem, const P& p, int l, int bf){
  float* hs = (float*)smem;      // 128
  float* xq = hs + 128;          // 128
  if (t < 128){
    float p0 = ld(p.niqp,2*n,bf), p1 = ld(p.niqp,2*n+1,bf);
    float a = fmaf(p0, p.wb[WO_QW1 + l*256 + t], fmaf(p1, p.wb[WO_QW1 + l*256 + 128 + t], p.wb[WO_QB1 + l*128 + t]));
    hs[t] = fmaxf(a, 0.f);
  }
  __syncthreads();
  if (t < 128){
    const float* W = p.wb + WO_QW2 + l*16384;
    float a0 = p.wb[WO_QB2 + l*128 + t], a1 = 0.f, a2 = 0.f, a3 = 0.f;
    #pragma unroll 8
    for (int k = 0; k < 128; k += 4){
      a0 = fmaf(hs[k],   W[k*128 + t],     a0);
      a1 = fmaf(hs[k+1], W[(k+1)*128 + t], a1);
      a2 = fmaf(hs[k+2], W[(k+2)*128 + t], a2);
      a3 = fmaf(hs[k+3], W[(k+3)*128 + t], a3);
    }
    float a = (a0+a1)+(a2+a3);
    p.qpe[(size_t)n*128 + t] = a;
    xq[t] = p.q[(size_t)n*128 + t] + a;
  }
  __syncthreads();
  const float* W = p.wb + WO_SAQKVW + l*49152;
  for (int c = t; c < 384; c += 256){
    float a0 = p.wb[WO_SAQKVB + l*384 + c], a1 = 0.f, a2 = 0.f, a3 = 0.f;
    #pragma unroll 8
    for (int k = 0; k < 128; k += 4){
      a0 = fmaf(xq[k],   W[(long)k*384 + c],     a0);
      a1 = fmaf(xq[k+1], W[(long)(k+1)*384 + c], a1);
      a2 = fmaf(xq[k+2], W[(long)(k+2)*384 + c], a2);
      a3 = fmaf(xq[k+3], W[(long)(k+3)*384 + c], a3);
    }
    p.tmp[(size_t)n*384 + c] = (a0+a1)+(a2+a3);
  }
}

// kv projection MFMA (keys + kpe -> kh/vh), 256 threads, LDS 17.4 KB
DEV void kvproj_block(int b, int t, unsigned char* smem, const P& p, int l){
  constexpr int XP = 136;
  unsigned short* xs = (unsigned short*)smem;
  int r0 = b * 64;
  // vectorized staging: 8 bf16 per iteration (16B loads from keys + kpe)
  for (int idx = t; idx < 64*16; idx += 256){
    int r = idx >> 4, u = idx & 15;
    int gr = r0 + r;
    int v = gr / 5600; int k = gr - v*5600;
    s16x8 kv = *(const s16x8*)&p.keys[(size_t)gr*128 + u*8];
    s16x8 pe = *(const s16x8*)&p.kpe[(size_t)k*128 + u*8];
    s16x8 ov;
    #pragma unroll
    for (int jj=0;jj<8;++jj){
      float a = u2f(((unsigned)(unsigned short)kv[jj])<<16) + u2f(((unsigned)(unsigned short)pe[jj])<<16);
      ov[jj] = (short)f2bu(a);
    }
    *(s16x8*)&xs[r*XP + u*8] = ov;
  }
  int wv = t >> 6;
  int lane = t & 63;
  int l16 = lane & 15, quad = lane >> 4;
  __syncthreads();
  f32x4 acc[4][4];
  #pragma unroll
  for (int mt=0;mt<4;++mt)
    #pragma unroll
    for (int nt=0;nt<4;++nt) acc[mt][nt] = (f32x4){0.f,0.f,0.f,0.f};
  #pragma unroll
  for (int kc = 0; kc < 4; ++kc){
    s16x8 bfr[4];
    #pragma unroll
    for (int nt = 0; nt < 4; ++nt){
      int col = wv*64 + nt*16 + l16;
      bfr[nt] = *(const s16x8*)&p.wkvT[((size_t)l*256 + col)*128 + kc*32 + quad*8];
    }
    s16x8 afr[4];
    #pragma unroll
    for (int mt = 0; mt < 4; ++mt)
      afr[mt] = *(const s16x8*)&xs[(mt*16 + l16)*XP + kc*32 + quad*8];
    #pragma unroll
    for (int mt = 0; mt < 4; ++mt)
      #pragma unroll
      for (int nt = 0; nt < 4; ++nt)
        acc[mt][nt] = __builtin_amdgcn_mfma_f32_16x16x32_bf16(afr[mt], bfr[nt], acc[mt][nt], 0, 0, 0);
  }
  float bv[4];
  bf16* op[4];
  long ntOff[4];
  #pragma unroll
  for (int nt = 0; nt < 4; ++nt){
    int c = wv*64 + nt*16 + l16;
    bv[nt] = p.wb[WO_CAQKVB + l*384 + 128 + c];
    int sel = c >> 7, ch = c & 127;
    int h = ch >> 4, d = ch & 15;
    op[nt] = sel ? p.vh : p.kh;
    ntOff[nt] = (long)h*89600 + d;
  }
  #pragma unroll
  for (int mt = 0; mt < 4; ++mt)
    #pragma unroll
    for (int i = 0; i < 4; ++i){
      int gr = r0 + mt*16 + quad*4 + i;
      int v = gr / 5600; int k = gr - v*5600;
      long rowOff = (long)v*716800 + (long)k*16;
      #pragma unroll
      for (int nt = 0; nt < 4; ++nt)
        op[nt][rowOff + ntOff[nt]] = f2b(acc[mt][nt][i] + bv[nt]);
    }
}

// self-attn + out-proj + LN1 + ca-q projection, 256 threads, LDS 2 KB
DEV void selfattn_block(int n, int t, unsigned char* smem, const P& p, int l){
  float* att  = (float*)smem;    // 128
  float* part = att + 128;       // 256
  float* redw = part + 256;      // 4
  float* xs2  = redw + 4;        // 128
  int h = t >> 5, j = t & 31;
  int vn = p.view[n];
  float4 qA, qB, qC, qD;
  {
    const float4* q4 = (const float4*)(p.tmp + (size_t)n*384 + h*16);
    qA = q4[0]; qB = q4[1]; qC = q4[2]; qD = q4[3];
    qA.x*=0.25f; qA.y*=0.25f; qA.z*=0.25f; qA.w*=0.25f;
    qB.x*=0.25f; qB.y*=0.25f; qB.z*=0.25f; qB.w*=0.25f;
    qC.x*=0.25f; qC.y*=0.25f; qC.z*=0.25f; qC.w*=0.25f;
    qD.x*=0.25f; qD.y*=0.25f; qD.z*=0.25f; qD.w*=0.25f;
  }
  float m = -INFINITY, s = 0.f, o[16];
  #pragma unroll
  for (int d=0; d<16; ++d) o[d]=0.f;
  for (int k = j; k < 200; k += 32){
    float l2;
    if (p.view[k] != vn){ l2 = -INFINITY; }
    else {
      const float4* kr4 = (const float4*)(p.tmp + (size_t)k*384 + 128 + h*16);
      float4 ka = kr4[0], kb = kr4[1], kc = kr4[2], kd = kr4[3];
      float l0 = fmaf(qA.x,ka.x, fmaf(qA.y,ka.y, fmaf(qA.z,ka.z, qA.w*ka.w)));
      float l1 = fmaf(qB.x,kb.x, fmaf(qB.y,kb.y, fmaf(qB.z,kb.z, qB.w*kb.w)));
      float l3 = fmaf(qC.x,kc.x, fmaf(qC.y,kc.y, fmaf(qC.z,kc.z, qC.w*kc.w)));
      float l4 = fmaf(qD.x,kd.x, fmaf(qD.y,kd.y, fmaf(qD.z,kd.z, qD.w*kd.w)));
      l2 = (l0+l1)+(l3+l4);
    }
    float mn = fmaxf(m, l2);
    float ea = (m > -3.0e38f) ? __expf(m - mn) : 0.f;
    float pp = (l2 > -3.0e38f) ? __expf(l2 - mn) : 0.f;
    s = s*ea + pp;
    const float4* vr4 = (const float4*)(p.tmp + (size_t)k*384 + 256 + h*16);
    float4 va = vr4[0], vb = vr4[1], vc = vr4[2], vd = vr4[3];
    o[0]=o[0]*ea+pp*va.x; o[1]=o[1]*ea+pp*va.y; o[2]=o[2]*ea+pp*va.z; o[3]=o[3]*ea+pp*va.w;
    o[4]=o[4]*ea+pp*vb.x; o[5]=o[5]*ea+pp*vb.y; o[6]=o[6]*ea+pp*vb.z; o[7]=o[7]*ea+pp*vb.w;
    o[8]=o[8]*ea+pp*vc.x; o[9]=o[9]*ea+pp*vc.y; o[10]=o[10]*ea+pp*vc.z; o[11]=o[11]*ea+pp*vc.w;
    o[12]=o[12]*ea+pp*vd.x; o[13]=o[13]*ea+pp*vd.y; o[14]=o[14]*ea+pp*vd.z; o[15]=o[15]*ea+pp*vd.w;
    m = mn;
  }
  // max-first merge across 32 lanes
  float M = m;
  #pragma unroll
  for (int off=16; off>=1; off>>=1) M = fmaxf(M, __shfl_xor(M, off));
  float sc = (m > -3.0e38f) ? __expf(m - M) : 0.f;
  s *= sc;
  #pragma unroll
  for (int d=0; d<16; ++d) o[d] *= sc;
  #pragma unroll
  for (int off=16; off>=1; off>>=1){
    s += __shfl_xor(s, off);
    #pragma unroll
    for (int d=0; d<16; ++d) o[d] += __shfl_xor(o[d], off);
  }
  if (j == 0){
    float inv = (s > 0.f) ? 1.f/s : 0.f;
    #pragma unroll
    for (int d=0; d<16; ++d) att[h*16 + d] = o[d]*inv;
  }
  __syncthreads();
  int tc = t & 127, half = t >> 7;
  {
    const float* W = p.wb + WO_SAOW + l*16384;
    int kb = half*64;
    float a0=0.f,a1=0.f,a2=0.f,a3=0.f;
    #pragma unroll
    for (int k = 0; k < 64; k += 4){
      a0 = fmaf(att[kb+k],   W[(kb+k)*128 + tc],   a0);
      a1 = fmaf(att[kb+k+1], W[(kb+k+1)*128 + tc], a1);
      a2 = fmaf(att[kb+k+2], W[(kb+k+2)*128 + tc], a2);
      a3 = fmaf(att[kb+k+3], W[(kb+k+3)*128 + tc], a3);
    }
    part[t] = (a0+a1)+(a2+a3);
  }
  __syncthreads();
  float v = (t<128) ? p.q[(size_t)n*128 + t] + part[t] + part[128+t] + p.wb[WO_SAOB + l*128 + t] : 0.f;
  float sv = wsum64(v);
  if ((t&63)==0) redw[t>>6] = sv;
  __syncthreads();
  float mean = (redw[0]+redw[1]+redw[2]+redw[3]) * (1.f/128.f);
  __syncthreads();
  float d = (t<128)? v-mean : 0.f;
  sv = wsum64(d*d);
  if ((t&63)==0) redw[t>>6] = sv;
  __syncthreads();
  float var = (redw[0]+redw[1]+redw[2]+redw[3]) * (1.f/128.f);
  float r = rsqrtf(var + 1e-5f);
  if (t<128){
    float qn = d*r*p.wb[WO_LN1G + l*128 + t] + p.wb[WO_LN1B + l*128 + t];
    p.q[(size_t)n*128 + t] = qn;
    xs2[t] = qn + p.qpe[(size_t)n*128 + t];
  }
  __syncthreads();
  {
    const float* Wc = p.wb + WO_CAQKVW + l*49152;
    int kb = half*64;
    float a0=0.f,a1=0.f,a2=0.f,a3=0.f;
    #pragma unroll
    for (int k = 0; k < 64; k += 4){
      a0 = fmaf(xs2[kb+k],   Wc[(long)(kb+k)*384 + tc],   a0);
      a1 = fmaf(xs2[kb+k+1], Wc[(long)(kb+k+1)*384 + tc], a1);
      a2 = fmaf(xs2[kb+k+2], Wc[(long)(kb+k+2)*384 + tc], a2);
      a3 = fmaf(xs2[kb+k+3], Wc[(long)(kb+k+3)*384 + tc], a3);
    }
    part[t] = (a0+a1)+(a2+a3);
  }
  __syncthreads();
  if (t<128)
    p.qca[(size_t)n*128 + t] = part[t] + part[128+t] + p.wb[WO_CAQKVB + l*384 + t];
}

// ================= packed launches =================
__global__ __launch_bounds__(256) void k_packA(P p, int l){
  __shared__ __align__(16) unsigned char smem[17920];
  int bf = get_bf(p.ln1g);
  int b = blockIdx.x;
  if (b < 88) kpe_block(b, threadIdx.x, smem, p, l, bf);
  else        saqkv_block(b - 88, threadIdx.x, smem, p, l, bf);
}

__global__ __launch_bounds__(256) void k_packB(P p, int l){
  __shared__ __align__(16) unsigned char smem[17408];
  int b = blockIdx.x;
  if (b < 525) kvproj_block(b, threadIdx.x, smem, p, l);
  else         selfattn_block(b - 525, threadIdx.x, smem, p, l);
}

// ================= cross-attention partial =================
// no-LDS, round-7 structure (1 query per 32-lane group, NSLICE=5) +
// split-butterfly o-reduction (16 shfl instead of 80; lanes end up owning dims)
__global__ __launch_bounds__(256) void k_cross_part(P p){
  int ch = blockIdx.x, h = blockIdx.y;
  int v = blockIdx.z / NSLICE, sl = blockIdx.z - v*NSLICE;
  int t = threadIdx.x;
  int k0 = ch*CK;
  int nq = p.qlp[v];
  const int* ql = p.qlp + 8 + v*200;
  int g = t >> 5, j = t & 31;
  const uint4* ks = (const uint4*)(p.kh + ((size_t)(v*8 + h)*5600 + k0)*16);
  const uint4* vs = (const uint4*)(p.vh + ((size_t)(v*8 + h)*5600 + k0)*16);
  const float2* fp = ((const float2*)p.fpos) + k0;
  // dim owned by this lane after split-butterfly
  int dim = 8*((j>>4)&1) + 4*((j>>3)&1) + 2*((j>>2)&1) + ((j>>1)&1);
  for (int pp = sl*8 + g; pp < nq; pp += 8*NSLICE){
    int n = ql[pp];
    float cx = p.ctr[2*n], cy = p.ctr[2*n+1];
    float is2 = p.sig2[n];
    const float4* q4 = (const float4*)(p.qca + (size_t)n*128 + h*16);
    float4 qA = q4[0], qB = q4[1], qC = q4[2], qD = q4[3];
    qA.x*=0.25f; qA.y*=0.25f; qA.z*=0.25f; qA.w*=0.25f;
    qB.x*=0.25f; qB.y*=0.25f; qB.z*=0.25f; qB.w*=0.25f;
    qC.x*=0.25f; qC.y*=0.25f; qC.z*=0.25f; qC.w*=0.25f;
    qD.x*=0.25f; qD.y*=0.25f; qD.z*=0.25f; qD.w*=0.25f;
    // phase A0: gaussian gates
    float gg[5];
    #pragma unroll
    for (int i = 0; i < 5; ++i){
      float2 pxy = fp[i*32 + j];
      float dx = cx - pxy.x, dy = cy - pxy.y;
      gg[i] = -(dx*dx + dy*dy) * is2;
    }
    // phase A1: logits (predicated K loads)
    float lg[5];
    #pragma unroll
    for (int i = 0; i < 5; ++i){
      if (gg[i] < LOG_EPS){ lg[i] = -INFINITY; continue; }
      int key = i*32 + j;
      uint4 a = ks[key*2], b = ks[key*2+1];
      float kf[16];
      unpack2(a.x, kf);    unpack2(a.y, kf+2);  unpack2(a.z, kf+4);  unpack2(a.w, kf+6);
      unpack2(b.x, kf+8);  unpack2(b.y, kf+10); unpack2(b.z, kf+12); unpack2(b.w, kf+14);
      float l0 = fmaf(qA.x,kf[0], fmaf(qA.y,kf[1], fmaf(qA.z,kf[2],  qA.w*kf[3])));
      float l1 = fmaf(qB.x,kf[4], fmaf(qB.y,kf[5], fmaf(qB.z,kf[6],  qB.w*kf[7])));
      float l3 = fmaf(qC.x,kf[8], fmaf(qC.y,kf[9], fmaf(qC.z,kf[10], qC.w*kf[11])));
      float l4 = fmaf(qD.x,kf[12],fmaf(qD.y,kf[13],fmaf(qD.z,kf[14], qD.w*kf[15])));
      lg[i] = gg[i] + ((l0+l1)+(l3+l4));
    }
    // phase B/C: lane max + group max
    float m = fmaxf(fmaxf(fmaxf(lg[0],lg[1]), fmaxf(lg[2],lg[3])), lg[4]);
    #pragma unroll
    for (int off=16; off>=1; off>>=1) m = fmaxf(m, __shfl_xor(m, off));
    // phase D: independent exps
    float pr[5], s = 0.f;
    #pragma unroll
    for (int i = 0; i < 5; ++i){
      pr[i] = (lg[i] > -3.0e38f) ? __expf(lg[i] - m) : 0.f;
      s += pr[i];
    }
    // phase E: PV accumulation (predicated V loads)
    float o[16];
    #pragma unroll
    for (int d=0; d<16; ++d) o[d] = 0.f;
    #pragma unroll
    for (int i = 0; i < 5; ++i){
      if (!(pr[i] > 0.f)) continue;
      int key = i*32 + j;
      uint4 a = vs[key*2], b = vs[key*2+1];
      float vf[16];
      unpack2(a.x, vf);    unpack2(a.y, vf+2);  unpack2(a.z, vf+4);  unpack2(a.w, vf+6);
      unpack2(b.x, vf+8);  unpack2(b.y, vf+10); unpack2(b.z, vf+12); unpack2(b.w, vf+14);
      float w = pr[i];
      #pragma unroll
      for (int d=0; d<16; ++d) o[d] = fmaf(w, vf[d], o[d]);
    }
    // s reduce (full butterfly, 5 ops)
    #pragma unroll
    for (int off=16; off>=1; off>>=1) s += __shfl_xor(s, off);
    // split-butterfly o reduce: 8+4+2+1 shfl, then final xor-1 add.
    // level M=16 (C=16): low keeps dims[0..8), hi keeps dims[8..16)
    {
      bool hi = (j & 16) != 0;
      #pragma unroll
      for (int d=0; d<8; ++d){
        float sel = hi ? o[d] : o[d+8];
        float r = __shfl_xor(sel, 16);
        o[d] = (hi ? o[d+8] : o[d]) + r;
      }
    }
    // level M=8 (C=8)
    {
      bool hi = (j & 8) != 0;
      #pragma unroll
      for (int d=0; d<4; ++d){
        float sel = hi ? o[d] : o[d+4];
        float r = __shfl_xor(sel, 8);
        o[d] = (hi ? o[d+4] : o[d]) + r;
      }
    }
    // level M=4 (C=4)
    {
      bool hi = (j & 4) != 0;
      #pragma unroll
      for (int d=0; d<2; ++d){
        float sel = hi ? o[d] : o[d+2];
        float r = __shfl_xor(sel, 4);
        o[d] = (hi ? o[d+2] : o[d]) + r;
      }
    }
    // level M=2 (C=2)
    {
      bool hi = (j & 2) != 0;
      float sel = hi ? o[0] : o[1];
      float r = __shfl_xor(sel, 2);
      o[0] = (hi ? o[1] : o[0]) + r;
    }
    // final: sum over bit0 partner
    o[0] += __shfl_xor(o[0], 1);
    int idx = (n*NC + ch)*8 + h;
    if (j == 0){
      p.pm[idx] = m; p.ps[idx] = s;
    }
    if ((j & 1) == 0){
      p.po[(size_t)idx*16 + dim] = o[0];
    }
  }
}

// ================= tail =================
__global__ __launch_bounds__(256) void k_tail(P p, int l){
  __shared__ float att[128];
  __shared__ float sm[2][128], ss[2][128], so[2][128];
  __shared__ float part[256];
  __shared__ float redw[4];
  __shared__ float xs[128];
  __shared__ float hs[256];
  __shared__ float redw6[24];
  __shared__ float bbv[8];
  int bf = get_bf(p.ln1g);
  int n = blockIdx.x, t = threadIdx.x;
  long outOff = (l==0) ? 45200L : 46400L;
  int last = (l==1);
  int tc = t & 127, half = t >> 7;
  {
    // batched combine: load all chunk triples, then max tree + independent exps
    int h = tc >> 4, d = tc & 15;
    int c0 = half ? 18 : 0, c1 = half ? NC : 18;
    float pmv[18], psv[18], pov[18];
    #pragma unroll
    for (int i = 0; i < 18; ++i){
      int c = c0 + i;
      bool ok = (c < c1);
      int cc = ok ? c : c0;
      int idx = (n*NC + cc)*8 + h;
      pmv[i] = ok ? p.pm[idx] : -INFINITY;
      psv[i] = ok ? p.ps[idx] : 0.f;
      pov[i] = ok ? p.po[(size_t)idx*16 + d] : 0.f;
    }
    float m = pmv[0];
    #pragma unroll
    for (int i = 1; i < 18; ++i) m = fmaxf(m, pmv[i]);
    float s = 0.f, o = 0.f;
    #pragma unroll
    for (int i = 0; i < 18; ++i){
      float e = (pmv[i] > -3.0e38f) ? __expf(pmv[i] - m) : 0.f;
      s = fmaf(psv[i], e, s);
      o = fmaf(pov[i], e, o);
    }
    sm[half][tc]=m; ss[half][tc]=s; so[half][tc]=o;
  }
  __syncthreads();
  if (t < 128){
    float m1=sm[0][t], m2=sm[1][t];
    float mn=fmaxf(m1,m2);
    float e1=(m1>-3.0e38f)?__expf(m1-mn):0.f, e2=(m2>-3.0e38f)?__expf(m2-mn):0.f;
    float s = ss[0][t]*e1 + ss[1][t]*e2;
    float o = so[0][t]*e1 + so[1][t]*e2;
    att[t] = (s>0.f)? o/s : 0.f;
  }
  __syncthreads();
  {
    const float* W = p.wb + WO_CAOW + l*16384;
    int kb = half*64;
    float a0=0.f,a1=0.f,a2=0.f,a3=0.f;
    #pragma unroll
    for (int k = 0; k < 64; k += 4){
      a0 = fmaf(att[kb+k],   W[(kb+k)*128 + tc],   a0);
      a1 = fmaf(att[kb+k+1], W[(kb+k+1)*128 + tc], a1);
      a2 = fmaf(att[kb+k+2], W[(kb+k+2)*128 + tc], a2);
      a3 = fmaf(att[kb+k+3], W[(kb+k+3)*128 + tc], a3);
    }
    part[t] = (a0+a1)+(a2+a3);
  }
  __syncthreads();
  float v = (t<128) ? p.q[(size_t)n*128 + t] + part[t] + part[128+t] + p.wb[WO_CAOB + l*128 + t] : 0.f;
  float sv = wsum64(v);
  if ((t&63)==0) redw[t>>6] = sv;
  __syncthreads();
  float mean = (redw[0]+redw[1]+redw[2]+redw[3]) * (1.f/128.f);
  __syncthreads();
  float d = (t<128)? v-mean : 0.f;
  sv = wsum64(d*d);
  if ((t&63)==0) redw[t>>6] = sv;
  __syncthreads();
  float var = (redw[0]+redw[1]+redw[2]+redw[3]) * (1.f/128.f);
  float r = rsqrtf(var + 1e-5f);
  if (t<128) xs[t] = d*r*p.wb[WO_LN2G + l*128 + t] + p.wb[WO_LN2B + l*128 + t];
  __syncthreads();
  {
    const float* W = p.wb + WO_FW1 + l*32768;
    float a0 = p.wb[WO_FB1 + l*256 + t], a1=0.f, a2=0.f, a3=0.f;
    #pragma unroll 8
    for (int k = 0; k < 128; k += 4){
      a0 = fmaf(xs[k],   W[k*256 + t],     a0);
      a1 = fmaf(xs[k+1], W[(k+1)*256 + t], a1);
      a2 = fmaf(xs[k+2], W[(k+2)*256 + t], a2);
      a3 = fmaf(xs[k+3], W[(k+3)*256 + t], a3);
    }
    hs[t] = fmaxf((a0+a1)+(a2+a3), 0.f);
  }
  __syncthreads();
  {
    const float* W = p.wb + WO_FW2 + l*32768;
    int kb = half*128;
    float a0=0.f,a1=0.f,a2=0.f,a3=0.f;
    #pragma unroll 8
    for (int k = 0; k < 128; k += 4){
      a0 = fmaf(hs[kb+k],   W[(kb+k)*128 + tc],   a0);
      a1 = fmaf(hs[kb+k+1], W[(kb+k+1)*128 + tc], a1);
      a2 = fmaf(hs[kb+k+2], W[(kb+k+2)*128 + tc], a2);
      a3 = fmaf(hs[kb+k+3], W[(kb+k+3)*128 + tc], a3);
    }
    part[t] = (a0+a1)+(a2+a3);
  }
  __syncthreads();
  v = (t<128) ? xs[t] + part[t] + part[128+t] + p.wb[WO_FB2 + l*128 + t] : 0.f;
  sv = wsum64(v);
  if ((t&63)==0) redw[t>>6] = sv;
  __syncthreads();
  mean = (redw[0]+redw[1]+redw[2]+redw[3]) * (1.f/128.f);
  __syncthreads();
  d = (t<128)? v-mean : 0.f;
  sv = wsum64(d*d);
  if ((t&63)==0) redw[t>>6] = sv;
  __syncthreads();
  var = (redw[0]+redw[1]+redw[2]+redw[3]) * (1.f/128.f);
  r = rsqrtf(var + 1e-5f);
  if (t<128){
    float q3 = d*r*p.wb[WO_LN3G + l*128 + t] + p.wb[WO_LN3B + l*128 + t];
    p.q[(size_t)n*128 + t] = q3;
    xs[t] = q3;
    if (last) st(p.out, (long)t*200 + n, q3, bf);
  }
  __syncthreads();
  {
    const float* W = p.wb + WO_PW1;
    int kb = half*64;
    float a0=0.f,a1=0.f,a2=0.f,a3=0.f;
    #pragma unroll
    for (int k = 0; k < 64; k += 4){
      a0 = fmaf(xs[kb+k],   W[(kb+k)*128 + tc],   a0);
      a1 = fmaf(xs[kb+k+1], W[(kb+k+1)*128 + tc], a1);
      a2 = fmaf(xs[kb+k+2], W[(kb+k+2)*128 + tc], a2);
      a3 = fmaf(xs[kb+k+3], W[(kb+k+3)*128 + tc], a3);
    }
    part[t] = (a0+a1)+(a2+a3);
  }
  __syncthreads();
  {
    float x = (t<128) ? fmaxf(part[t] + part[128+t] + p.wb[WO_PB1 + t], 0.f) : 0.f;
    #pragma unroll
    for (int c=0;c<6;++c){
      float val = wsum64((t<128) ? x * p.wb[WO_PW2 + t*6 + c] : 0.f);
      if ((t&63)==0) redw6[(t>>6)*6 + c] = val;
    }
  }
  __syncthreads();
  if (t < 6){
    float raw = redw6[t] + redw6[6+t] + redw6[12+t] + redw6[18+t] + p.wb[WO_PB2 + t];
    if (t < 2) raw += ld(p.niqp, 2*n + t, bf);
    float svv = sigm(raw);
    st(p.out, outOff + n*6 + t, svv, bf);
    bbv[t] = svv;
  }
  __syncthreads();
  if (t == 0){
    float dxv = sigm(bbv[2]) * IMGX;
    float dyv = sigm(bbv[3]) * IMGY;
    float rad = ceilf(sqrtf(dxv*dxv + dyv*dyv) * 0.5f);
    float sg = (rad*2.f + 1.f) * (1.f/6.f);
    p.sig2[n] = 1.f/(2.f*sg*sg);
  }
}

// ================= launch =================
extern "C" void kernel_launch(void* const* d_in, const int* in_sizes, int n_in,
                              void* d_out, int out_size, void* d_ws, size_t ws_size,
                              hipStream_t stream){
  const void* iqf   = d_in[0];
  const void* niqp  = d_in[1];
  const void* iff   = d_in[2];
  const void* nifp  = d_in[3];
  const void* l2i   = d_in[4];
  const int*  view  = (const int*)d_in[5];
  const void* ln1_g = d_in[14];

  float* fw = (float*)d_ws;
  int*   qlp  = (int*)(fw + OFF_QL);
  float* wb   = fw + OFF_WB;
  bf16* bw   = (bf16*)((char*)d_ws + F_TOTAL*sizeof(float));
  bf16* wkvT_m = bw + B_WKVT;
  bf16* kw2T_m = bw + B_KW2T;

  P p;
  p.nifp = nifp; p.iff = iff; p.niqp = niqp; p.ln1g = ln1_g;
  p.view = view; p.qlp = qlp;
  p.wb = wb;
  p.q = fw + OFF_Q; p.qpe = fw + OFF_QPE; p.qca = fw + OFF_QCA; p.tmp = fw + OFF_TMP;
  p.pm = fw + OFF_PM; p.ps = fw + OFF_PS; p.po = fw + OFF_PO;
  p.fpos = fw + OFF_FPOS; p.ctr = fw + OFF_CTR; p.sig2 = fw + OFF_SIG;
  p.kw2T = kw2T_m; p.wkvT = wkvT_m; p.keys = bw + B_KEYS;
  p.kh = bw + B_KH; p.vh = bw + B_VH; p.kpe = bw + B_KPE;
  p.out = d_out;

  CvtArgs ca;
  ca.s[0]  = {d_in[6],  WO_SAQKVW, 98304};
  ca.s[1]  = {d_in[7],  WO_SAQKVB, 768};
  ca.s[2]  = {d_in[8],  WO_SAOW,   32768};
  ca.s[3]  = {d_in[9],  WO_SAOB,   256};
  ca.s[4]  = {d_in[10], WO_CAQKVW, 98304};
  ca.s[5]  = {d_in[11], WO_CAQKVB, 768};
  ca.s[6]  = {d_in[12], WO_CAOW,   32768};
  ca.s[7]  = {d_in[13], WO_CAOB,   256};
  ca.s[8]  = {d_in[14], WO_LN1G,   256};
  ca.s[9]  = {d_in[15], WO_LN1B,   256};
  ca.s[10] = {d_in[16], WO_LN2G,   256};
  ca.s[11] = {d_in[17], WO_LN2B,   256};
  ca.s[12] = {d_in[18], WO_LN3G,   256};
  ca.s[13] = {d_in[19], WO_LN3B,   256};
  ca.s[14] = {d_in[20], WO_FW1,    65536};
  ca.s[15] = {d_in[21], WO_FB1,    512};
  ca.s[16] = {d_in[22], WO_FW2,    65536};
  ca.s[17] = {d_in[23], WO_FB2,    256};
  ca.s[18] = {d_in[24], WO_QW1,    512};
  ca.s[19] = {d_in[25], WO_QB1,    256};
  ca.s[20] = {d_in[26], WO_QW2,    32768};
  ca.s[21] = {d_in[27], WO_QB2,    256};
  ca.s[22] = {d_in[28], WO_KW1,    512};
  ca.s[23] = {d_in[29], WO_KB1,    256};
  ca.s[24] = {d_in[31], WO_KB2,    256};
  ca.s[25] = {d_in[32], WO_PW1,    16384};
  ca.s[26] = {d_in[33], WO_PB1,    128};
  ca.s[27] = {d_in[34], WO_PW2,    768};
  ca.s[28] = {d_in[35], WO_PB2,    6};

  k_cvt<<<dim3(30,8), 256, 0, stream>>>(ca, wb, qlp, view, ln1_g);
  k_wT<<<dim3(384,2), 128, 0, stream>>>(d_in[10], d_in[30], wkvT_m, kw2T_m, ln1_g);
  k_transpose<<<dim3(175,4,6), dim3(32,8), 0, stream>>>(iff, bw + B_KEYS, ln1_g);
  k_prep2<<<200, 128, 0, stream>>>(niqp, l2i, nifp, view, iqf, p.ctr, p.fpos, p.q, wb, p.sig2, d_out, ln1_g);

  for (int l = 0; l < 2; ++l){
    k_packA<<<288, 256, 0, stream>>>(p, l);
    k_packB<<<725, 256, 0, stream>>>(p, l);
    k_cross_part<<<dim3(NC,8,6*NSLICE), 256, 0, stream>>>(p);
    k_tail<<<200, 256, 0, stream>>>(p, l);
  }
}